// Round 5
// baseline (246.190 us; speedup 1.0000x reference)
//
#include <hip/hip_runtime.h>

typedef unsigned int u32;

#define NPS   (256 * 1 * 128 * 128)   // elements per sample = 4194304
#define NPS4  (NPS / 4)               // 1048576 float4 per sample
#define NSAMP 8
#define NB    2048                    // threshold-histogram buckets
#define PREDN 16384                   // H*W
#define SPB   128                     // phase2 blocks per sample
#define STRIDE4 (SPB * 256)           // 32768 float4 stride (multiple of 4096!)
#define NSTEP (NPS4 / STRIDE4)        // 32 steps per thread
#define ZONE  4                       // zone half-width in buckets
#define PBPS  16                      // phase1 blocks per sample

// acc layout per sample (8 u32 slots): 0 cnt_obs, 1 cnt_z, 2 cnt_hi, 3 cnt_x,
//                                      4 sum_z(f32), 5 sum_hi(f32), 6 sum_x(f32), 7 pad
#define ACC_STRIDE 8

// ---------------- impute: pred[h][w] = MLP(x_emb[h] * y_emb[w]) ----------------
__global__ __launch_bounds__(256) void impute_kernel(
    const float* __restrict__ xe, const float* __restrict__ ye,
    const float* __restrict__ w1, const float* __restrict__ b1,
    const float* __restrict__ w2, const float* __restrict__ b2,
    float* __restrict__ pred)
{
    __shared__ float sw1[64 * 32];
    __shared__ float sb1[32];
    __shared__ float sw2[32];
    __shared__ float sb2;
    for (int i = threadIdx.x; i < 2048; i += 256) sw1[i] = w1[i];
    if (threadIdx.x < 32) { sb1[threadIdx.x] = b1[threadIdx.x]; sw2[threadIdx.x] = w2[threadIdx.x]; }
    if (threadIdx.x == 0) sb2 = b2[0];
    __syncthreads();

    int t = blockIdx.x * 256 + threadIdx.x;
    if (t >= PREDN) return;
    int h = t >> 7, w = t & 127;

    float acc[32];
#pragma unroll
    for (int j = 0; j < 32; ++j) acc[j] = sb1[j];

    const float* xr = xe + h * 64;
    const float* yr = ye + w * 64;
#pragma unroll 4
    for (int e = 0; e < 64; ++e) {
        float p = xr[e] * yr[e];
#pragma unroll
        for (int j = 0; j < 32; ++j) acc[j] = fmaf(p, sw1[e * 32 + j], acc[j]);
    }
    float o = sb2;
#pragma unroll
    for (int j = 0; j < 32; ++j) {
        float a = acc[j];
        float s = a / (1.0f + expf(-a));   // silu
        o = fmaf(s, sw2[j], o);
    }
    pred[t] = o;
}

// ---------------- phase 1a: subsampled per-block histogram + global merge ----------------
__global__ __launch_bounds__(256) void phase1_hist(
    const float* __restrict__ mask, const float* __restrict__ rnd,
    u32* __restrict__ ghist, u32* __restrict__ gobs)
{
    __shared__ u32 hist[NB];
    __shared__ u32 lobs;
    for (int i = threadIdx.x; i < NB; i += 256) hist[i] = 0u;
    if (threadIdx.x == 0) lobs = 0u;
    __syncthreads();

    const int s = blockIdx.y;
    const float4* m4 = (const float4*)(mask + (size_t)s * NPS);
    const float4* r4 = (const float4*)(rnd  + (size_t)s * NPS);

    u32 myobs = 0;
#pragma unroll
    for (int i = 0; i < 2; ++i) {
        int r = blockIdx.x * 512 + i * 256 + threadIdx.x;   // run id
        int base4 = r * 128;                                // float4 index of run start
        float4 mm[4], rr[4];
#pragma unroll
        for (int q = 0; q < 4; ++q) { mm[q] = m4[base4 + q]; rr[q] = r4[base4 + q]; }
#pragma unroll
        for (int q = 0; q < 4; ++q) {
#pragma unroll
            for (int j = 0; j < 4; ++j) {
                float m = (&mm[q].x)[j];
                if (m != 0.0f) {
                    myobs++;
                    float rm = (&rr[q].x)[j] * m;
                    if (rm > 0.0f) {
                        int b = (int)(rm * (float)NB);
                        b = b < NB ? b : NB - 1;
                        atomicAdd(&hist[b], 1u);
                    }
                }
            }
        }
    }
    atomicAdd(&lobs, myobs);
    __syncthreads();

    u32* gh = ghist + s * NB;
    for (int i = threadIdx.x; i < NB; i += 256) {
        u32 c = hist[i];
        if (c) atomicAdd(&gh[i], c);
    }
    if (threadIdx.x == 0) atomicAdd(&gobs[s], lobs);
}

// ---------------- phase 1b: per-sample threshold bucket ----------------
__global__ __launch_bounds__(256) void phase1_select(
    const u32* __restrict__ ghist, const u32* __restrict__ gobs,
    int* __restrict__ bx_out)
{
    const int s = blockIdx.x;
    __shared__ u32 hist[NB];
    __shared__ u32 tcnt[256];
    const u32* gh = ghist + s * NB;
    for (int i = threadIdx.x; i < NB; i += 256) hist[i] = gh[i];
    __syncthreads();

    {
        int t = threadIdx.x;
        u32 c = 0;
#pragma unroll
        for (int i = 0; i < NB / 256; ++i) c += hist[t * (NB / 256) + i];
        tcnt[t] = c;
    }
    __syncthreads();

    if (threadIdx.x == 0) {
        const int CPT = NB / 256;
        float ksub = 0.1f * (float)gobs[s];
        long long cum = 0; int bx = 0; int tx = -1;
        for (int t = 255; t >= 0; --t) {
            if ((float)(cum + (long long)tcnt[t]) >= ksub) { tx = t; break; }
            cum += tcnt[t];
        }
        if (tx >= 0) {
            bx = tx * CPT;
            for (int b = tx * CPT + CPT - 1; b >= tx * CPT; --b) {
                if ((float)(cum + (long long)hist[b]) >= ksub) { bx = b; break; }
                cum += hist[b];
            }
        }
        bx_out[s] = bx;
    }
}

// ---------------- phase 2: interleaved streaming classify, 4-slot pipeline ----------------
__global__ __launch_bounds__(256, 4) void phase2_kernel(
    const float* __restrict__ data, const float* __restrict__ mask,
    const float* __restrict__ rnd, const float* __restrict__ pred,
    const int* __restrict__ bx_in, u32* __restrict__ acc)
{
    const int s = blockIdx.y;
    const int bx = bx_in[s];
    const int zlo = bx - ZONE < 0 ? 0 : bx - ZONE;
    const int zhi = bx + ZONE > NB - 1 ? NB - 1 : bx + ZONE;
    const float tlo = (float)zlo / (float)NB;
    const float thi = (float)(zhi + 1) / (float)NB;

    const int gid = blockIdx.x * 256 + threadIdx.x;       // [0, STRIDE4)
    const size_t base4 = (size_t)s * NPS4 + gid;

    const float4* __restrict__ d4 = (const float4*)data + base4;
    const float4* __restrict__ m4 = (const float4*)mask + base4;
    const float4* __restrict__ r4 = (const float4*)rnd  + base4;

    // pred index is constant per thread: STRIDE4 % 4096 == 0
    const float4 pp = ((const float4*)pred)[gid & 4095];

    u32 cobs = 0, cz = 0, chi = 0, cx = 0;
    float sz = 0.0f, shi = 0.0f, sx = 0.0f;

    float4 dA, mA, rA, dB, mB, rB, dC, mC, rC, dD, mD, rD;

#define LOADS(D,M,R,i) do { \
        D = d4[(size_t)(i) * STRIDE4]; \
        M = m4[(size_t)(i) * STRIDE4]; \
        R = r4[(size_t)(i) * STRIDE4]; \
    } while (0)

#define PROCS(DD,MM,RR) do { \
        _Pragma("unroll") \
        for (int j = 0; j < 4; ++j) { \
            float m_ = (&MM.x)[j]; \
            bool obs_ = (m_ != 0.0f); \
            float rm_ = (&RR.x)[j] * m_; \
            float rs_ = (&DD.x)[j] - (&pp.x)[j]; \
            float r2_ = rs_ * rs_; \
            bool z_  = obs_ && (rm_ <= 0.0f); \
            bool hi_ = obs_ && (rm_ > thi); \
            bool x_  = obs_ && (rm_ > tlo) && (rm_ <= thi) && (rm_ > 0.0f); \
            cobs += obs_ ? 1u : 0u; \
            cz   += z_   ? 1u : 0u; \
            chi  += hi_  ? 1u : 0u; \
            cx   += x_   ? 1u : 0u; \
            sz  += z_  ? r2_ : 0.0f; \
            shi += hi_ ? r2_ : 0.0f; \
            sx  += x_  ? r2_ : 0.0f; \
        } \
    } while (0)

#define SB __builtin_amdgcn_sched_barrier(0)

    LOADS(dA, mA, rA, 0);
    LOADS(dB, mB, rB, 1);
    LOADS(dC, mC, rC, 2);
    LOADS(dD, mD, rD, 3);
    SB;
#pragma unroll
    for (int i = 0; i < NSTEP; i += 4) {
        PROCS(dA, mA, rA); if (i + 4 < NSTEP) LOADS(dA, mA, rA, i + 4); SB;
        PROCS(dB, mB, rB); if (i + 5 < NSTEP) LOADS(dB, mB, rB, i + 5); SB;
        PROCS(dC, mC, rC); if (i + 6 < NSTEP) LOADS(dC, mC, rC, i + 6); SB;
        PROCS(dD, mD, rD); if (i + 7 < NSTEP) LOADS(dD, mD, rD, i + 7); SB;
    }

#undef LOADS
#undef PROCS
#undef SB

    // wave-level shuffle reduction
#pragma unroll
    for (int off = 32; off >= 1; off >>= 1) {
        cobs += __shfl_down(cobs, off, 64);
        cz   += __shfl_down(cz, off, 64);
        chi  += __shfl_down(chi, off, 64);
        cx   += __shfl_down(cx, off, 64);
        sz   += __shfl_down(sz, off, 64);
        shi  += __shfl_down(shi, off, 64);
        sx   += __shfl_down(sx, off, 64);
    }

    __shared__ u32   wc[4][4];
    __shared__ float wsm[4][3];
    const int wave = threadIdx.x >> 6;
    const int lane = threadIdx.x & 63;
    if (lane == 0) {
        wc[wave][0] = cobs; wc[wave][1] = cz; wc[wave][2] = chi; wc[wave][3] = cx;
        wsm[wave][0] = sz; wsm[wave][1] = shi; wsm[wave][2] = sx;
    }
    __syncthreads();
    if (threadIdx.x == 0) {
        u32 C[4] = {0, 0, 0, 0}; float S[3] = {0.f, 0.f, 0.f};
#pragma unroll
        for (int w = 0; w < 4; ++w) {
#pragma unroll
            for (int i = 0; i < 4; ++i) C[i] += wc[w][i];
#pragma unroll
            for (int i = 0; i < 3; ++i) S[i] += wsm[w][i];
        }
        u32* a = acc + s * ACC_STRIDE;
        if (C[0]) atomicAdd(&a[0], C[0]);
        if (C[1]) atomicAdd(&a[1], C[1]);
        if (C[2]) atomicAdd(&a[2], C[2]);
        if (C[3]) atomicAdd(&a[3], C[3]);
        float* fa = (float*)a;
#if defined(__HIP_DEVICE_COMPILE__)
        if (S[0] != 0.f) unsafeAtomicAdd(&fa[4], S[0]);
        if (S[1] != 0.f) unsafeAtomicAdd(&fa[5], S[1]);
        if (S[2] != 0.f) unsafeAtomicAdd(&fa[6], S[2]);
#else
        if (S[0] != 0.f) atomicAdd(&fa[4], S[0]);
        if (S[1] != 0.f) atomicAdd(&fa[5], S[1]);
        if (S[2] != 0.f) atomicAdd(&fa[6], S[2]);
#endif
    }
}

// ---------------- finalize ----------------
__global__ void finalize_kernel(const u32* __restrict__ acc, float* __restrict__ out)
{
    if (blockIdx.x == 0 && threadIdx.x == 0) {
        double S = 0.0, C = 0.0;
        for (int s = 0; s < NSAMP; ++s) {
            const u32* a = acc + s * ACC_STRIDE;
            const float* fa = (const float*)a;
            long long nobs = (long long)a[0];
            long long cz   = (long long)a[1];
            long long chi  = (long long)a[2];
            long long cx   = (long long)a[3];
            double sz = fa[4], shi = fa[5], sx = fa[6];
            long long k = (long long)rintf(0.1f * (float)nobs);   // jnp.round semantics
            long long need = k - chi;
            if (need < 0) need = 0;
            if (need > cx) need = cx;
            double frac = cx > 0 ? (double)need / (double)cx : 0.0;
            S += shi + frac * sx + sz;
            C += (double)(chi + need + cz);
        }
        out[0] = (float)(S / (C > 0.0 ? C : 1.0));
    }
}

extern "C" void kernel_launch(void* const* d_in, const int* in_sizes, int n_in,
                              void* d_out, int out_size, void* d_ws, size_t ws_size,
                              hipStream_t stream)
{
    const float* data = (const float*)d_in[0];
    const float* mask = (const float*)d_in[1];
    const float* rnd  = (const float*)d_in[4];
    const float* xe   = (const float*)d_in[5];
    const float* ye   = (const float*)d_in[6];
    const float* w1   = (const float*)d_in[7];
    const float* b1   = (const float*)d_in[8];
    const float* w2   = (const float*)d_in[9];
    const float* b2   = (const float*)d_in[10];
    float* out = (float*)d_out;

    char* ws = (char*)d_ws;
    float* pred  = (float*)(ws);               // 65536 B
    u32*   ghist = (u32*)(ws + 65536);         // 8*2048*4 = 65536 B
    u32*   gobs  = (u32*)(ws + 131072);        // 32 B
    int*   bx    = (int*)(ws + 131104);        // 32 B
    u32*   acc   = (u32*)(ws + 131136);        // 256 B

    hipMemsetAsync(ws + 65536, 0, 65536 + 32 + 32 + 256, stream);

    dim3 g1(PBPS, NSAMP);
    phase1_hist<<<g1, 256, 0, stream>>>(mask, rnd, ghist, gobs);
    phase1_select<<<NSAMP, 256, 0, stream>>>(ghist, gobs, bx);
    impute_kernel<<<(PREDN + 255) / 256, 256, 0, stream>>>(xe, ye, w1, b1, w2, b2, pred);

    dim3 g2(SPB, NSAMP);
    phase2_kernel<<<g2, 256, 0, stream>>>(data, mask, rnd, pred, bx, acc);

    finalize_kernel<<<1, 64, 0, stream>>>(acc, out);
}

// Round 6
// 147.520 us; speedup vs baseline: 1.6689x; 1.6689x over previous
//
#include <hip/hip_runtime.h>

typedef unsigned int u32;

#define NPS   (256 * 1 * 128 * 128)   // elements per sample = 4194304
#define NPS4  (NPS / 4)               // 1048576 float4 per sample
#define NSAMP 8
#define NB    2048                    // threshold-histogram buckets
#define PREDN 16384                   // H*W
#define BPS   256                     // blocks per sample in pass A/B
#define CHUNK (NPS / BPS)             // 16384 elements per block
#define CH4   (CHUNK / 4)             // 4096 float4 per block
#define ZONE  4                       // zone half-width in buckets
#define PBPS  16                      // phase1 blocks per sample

// acc layout per sample (8 u32 slots): 0 cnt_obs, 1 cnt_z, 2 cnt_hi, 3 cnt_x,
//                                      4 sum_z(f32), 5 sum_hi(f32), 6 sum_x(f32), 7 pad
#define ACC_STRIDE 8

// ---------------- impute: pred[h][w] = MLP(x_emb[h] * y_emb[w]) ----------------
__global__ __launch_bounds__(256) void impute_kernel(
    const float* __restrict__ xe, const float* __restrict__ ye,
    const float* __restrict__ w1, const float* __restrict__ b1,
    const float* __restrict__ w2, const float* __restrict__ b2,
    float* __restrict__ pred)
{
    __shared__ float sw1[64 * 32];
    __shared__ float sb1[32];
    __shared__ float sw2[32];
    __shared__ float sb2;
    for (int i = threadIdx.x; i < 2048; i += 256) sw1[i] = w1[i];
    if (threadIdx.x < 32) { sb1[threadIdx.x] = b1[threadIdx.x]; sw2[threadIdx.x] = w2[threadIdx.x]; }
    if (threadIdx.x == 0) sb2 = b2[0];
    __syncthreads();

    int t = blockIdx.x * 256 + threadIdx.x;
    if (t >= PREDN) return;
    int h = t >> 7, w = t & 127;

    float acc[32];
#pragma unroll
    for (int j = 0; j < 32; ++j) acc[j] = sb1[j];

    const float* xr = xe + h * 64;
    const float* yr = ye + w * 64;
#pragma unroll 4
    for (int e = 0; e < 64; ++e) {
        float p = xr[e] * yr[e];
#pragma unroll
        for (int j = 0; j < 32; ++j) acc[j] = fmaf(p, sw1[e * 32 + j], acc[j]);
    }
    float o = sb2;
#pragma unroll
    for (int j = 0; j < 32; ++j) {
        float a = acc[j];
        float s = a / (1.0f + expf(-a));   // silu
        o = fmaf(s, sw2[j], o);
    }
    pred[t] = o;
}

// ---------------- phase 1a: subsampled per-block histogram + global merge ----------------
__global__ __launch_bounds__(256) void phase1_hist(
    const float* __restrict__ mask, const float* __restrict__ rnd,
    u32* __restrict__ ghist, u32* __restrict__ gobs)
{
    __shared__ u32 hist[NB];
    __shared__ u32 lobs;
    for (int i = threadIdx.x; i < NB; i += 256) hist[i] = 0u;
    if (threadIdx.x == 0) lobs = 0u;
    __syncthreads();

    const int s = blockIdx.y;
    const float4* m4 = (const float4*)(mask + (size_t)s * NPS);
    const float4* r4 = (const float4*)(rnd  + (size_t)s * NPS);

    u32 myobs = 0;
#pragma unroll
    for (int i = 0; i < 2; ++i) {
        int r = blockIdx.x * 512 + i * 256 + threadIdx.x;   // run id
        int base4 = r * 128;                                // float4 index of run start
        float4 mm[4], rr[4];
#pragma unroll
        for (int q = 0; q < 4; ++q) { mm[q] = m4[base4 + q]; rr[q] = r4[base4 + q]; }
#pragma unroll
        for (int q = 0; q < 4; ++q) {
#pragma unroll
            for (int j = 0; j < 4; ++j) {
                float m = (&mm[q].x)[j];
                if (m != 0.0f) {
                    myobs++;
                    float rm = (&rr[q].x)[j] * m;
                    if (rm > 0.0f) {
                        int b = (int)(rm * (float)NB);
                        b = b < NB ? b : NB - 1;
                        atomicAdd(&hist[b], 1u);
                    }
                }
            }
        }
    }
    atomicAdd(&lobs, myobs);
    __syncthreads();

    u32* gh = ghist + s * NB;
    for (int i = threadIdx.x; i < NB; i += 256) {
        u32 c = hist[i];
        if (c) atomicAdd(&gh[i], c);
    }
    if (threadIdx.x == 0) atomicAdd(&gobs[s], lobs);
}

// ---------------- phase 1b: per-sample threshold bucket ----------------
__global__ __launch_bounds__(256) void phase1_select(
    const u32* __restrict__ ghist, const u32* __restrict__ gobs,
    int* __restrict__ bx_out)
{
    const int s = blockIdx.x;
    __shared__ u32 hist[NB];
    __shared__ u32 tcnt[256];
    const u32* gh = ghist + s * NB;
    for (int i = threadIdx.x; i < NB; i += 256) hist[i] = gh[i];
    __syncthreads();

    {
        int t = threadIdx.x;
        u32 c = 0;
#pragma unroll
        for (int i = 0; i < NB / 256; ++i) c += hist[t * (NB / 256) + i];
        tcnt[t] = c;
    }
    __syncthreads();

    if (threadIdx.x == 0) {
        const int CPT = NB / 256;
        float ksub = 0.1f * (float)gobs[s];
        long long cum = 0; int bx = 0; int tx = -1;
        for (int t = 255; t >= 0; --t) {
            if ((float)(cum + (long long)tcnt[t]) >= ksub) { tx = t; break; }
            cum += tcnt[t];
        }
        if (tx >= 0) {
            bx = tx * CPT;
            for (int b = tx * CPT + CPT - 1; b >= tx * CPT; --b) {
                if ((float)(cum + (long long)hist[b]) >= ksub) { bx = b; break; }
                cum += hist[b];
            }
        }
        bx_out[s] = bx;
    }
}

// ---------------- pass A: mask+rnd -> 2-bit class bitmap + counts ----------------
// class: 0 none, 1 z (obs & rm<=0), 2 hi (obs & rm>thi), 3 zone (obs & tlo<rm<=thi)
__global__ __launch_bounds__(256) void passA_kernel(
    const float* __restrict__ mask, const float* __restrict__ rnd,
    const int* __restrict__ bx_in, uint4* __restrict__ bitmap,
    u32* __restrict__ acc)
{
    const int s = blockIdx.y;
    const int bx = bx_in[s];
    const int zlo = bx - ZONE < 0 ? 0 : bx - ZONE;
    const int zhi = bx + ZONE > NB - 1 ? NB - 1 : bx + ZONE;
    const float tlo = (float)zlo / (float)NB;       // >= 0
    const float thi = (float)(zhi + 1) / (float)NB;

    const int tid = threadIdx.x;
    const size_t base4 = (size_t)s * NPS4 + (size_t)blockIdx.x * CH4;
    const float4* __restrict__ m4 = (const float4*)mask + base4;
    const float4* __restrict__ r4 = (const float4*)rnd  + base4;

    u32 cobs = 0, cz = 0, chi = 0, cx = 0;
    u32 words[4];

#pragma unroll
    for (int g = 0; g < 4; ++g) {
        float4 mm[4], rr[4];
#pragma unroll
        for (int ss = 0; ss < 4; ++ss) {
            int v = (g * 4 + ss) * 256 + tid;
            mm[ss] = m4[v]; rr[ss] = r4[v];
        }
        u32 w = 0;
#pragma unroll
        for (int ss = 0; ss < 4; ++ss) {
#pragma unroll
            for (int j = 0; j < 4; ++j) {
                float m = (&mm[ss].x)[j];
                bool obs = (m != 0.0f);
                float rm = (&rr[ss].x)[j] * m;
                u32 c = obs ? (rm <= 0.0f ? 1u : (rm > thi ? 2u : (rm > tlo ? 3u : 0u))) : 0u;
                w |= c << (8 * ss + 2 * j);
                cobs += obs ? 1u : 0u;
                cz   += (c == 1u) ? 1u : 0u;
                chi  += (c == 2u) ? 1u : 0u;
                cx   += (c == 3u) ? 1u : 0u;
            }
        }
        words[g] = w;
    }

    // coalesced bitmap store: one uint4 per thread
    bitmap[((size_t)s * BPS + blockIdx.x) * 256 + tid] =
        make_uint4(words[0], words[1], words[2], words[3]);

    // block reduce counts
#pragma unroll
    for (int off = 32; off >= 1; off >>= 1) {
        cobs += __shfl_down(cobs, off, 64);
        cz   += __shfl_down(cz, off, 64);
        chi  += __shfl_down(chi, off, 64);
        cx   += __shfl_down(cx, off, 64);
    }
    __shared__ u32 wc[4][4];
    const int wave = tid >> 6, lane = tid & 63;
    if (lane == 0) { wc[wave][0] = cobs; wc[wave][1] = cz; wc[wave][2] = chi; wc[wave][3] = cx; }
    __syncthreads();
    if (tid == 0) {
        u32 C[4] = {0, 0, 0, 0};
#pragma unroll
        for (int w = 0; w < 4; ++w)
#pragma unroll
            for (int i = 0; i < 4; ++i) C[i] += wc[w][i];
        u32* a = acc + s * ACC_STRIDE;
        if (C[0]) atomicAdd(&a[0], C[0]);
        if (C[1]) atomicAdd(&a[1], C[1]);
        if (C[2]) atomicAdd(&a[2], C[2]);
        if (C[3]) atomicAdd(&a[3], C[3]);
    }
}

// ---------------- pass B: data + bitmap -> sums ----------------
__global__ __launch_bounds__(256) void passB_kernel(
    const float* __restrict__ data, const float* __restrict__ pred,
    const uint4* __restrict__ bitmap, u32* __restrict__ acc)
{
    const int s = blockIdx.y;
    const int tid = threadIdx.x;
    const size_t base4 = (size_t)s * NPS4 + (size_t)blockIdx.x * CH4;
    const float4* __restrict__ d4 = (const float4*)data + base4;
    const float4* __restrict__ p4 = (const float4*)pred;   // block spans one pred period

    const uint4 bw = bitmap[((size_t)s * BPS + blockIdx.x) * 256 + tid];
    const u32 wrd[4] = {bw.x, bw.y, bw.z, bw.w};

    float sz = 0.0f, shi = 0.0f, sx = 0.0f;

#pragma unroll
    for (int g = 0; g < 4; ++g) {
        float4 dd[4], pp[4];
#pragma unroll
        for (int ss = 0; ss < 4; ++ss) {
            int v = (g * 4 + ss) * 256 + tid;
            dd[ss] = d4[v]; pp[ss] = p4[v];
        }
        const u32 w = wrd[g];
#pragma unroll
        for (int ss = 0; ss < 4; ++ss) {
#pragma unroll
            for (int j = 0; j < 4; ++j) {
                u32 c = (w >> (8 * ss + 2 * j)) & 3u;
                float rs = (&dd[ss].x)[j] - (&pp[ss].x)[j];
                float r2 = rs * rs;
                sz  += (c == 1u) ? r2 : 0.0f;
                shi += (c == 2u) ? r2 : 0.0f;
                sx  += (c == 3u) ? r2 : 0.0f;
            }
        }
    }

#pragma unroll
    for (int off = 32; off >= 1; off >>= 1) {
        sz  += __shfl_down(sz, off, 64);
        shi += __shfl_down(shi, off, 64);
        sx  += __shfl_down(sx, off, 64);
    }
    __shared__ float wsm[4][3];
    const int wave = tid >> 6, lane = tid & 63;
    if (lane == 0) { wsm[wave][0] = sz; wsm[wave][1] = shi; wsm[wave][2] = sx; }
    __syncthreads();
    if (tid == 0) {
        float S[3] = {0.f, 0.f, 0.f};
#pragma unroll
        for (int w = 0; w < 4; ++w)
#pragma unroll
            for (int i = 0; i < 3; ++i) S[i] += wsm[w][i];
        float* fa = (float*)(acc + s * ACC_STRIDE);
#if defined(__HIP_DEVICE_COMPILE__)
        if (S[0] != 0.f) unsafeAtomicAdd(&fa[4], S[0]);
        if (S[1] != 0.f) unsafeAtomicAdd(&fa[5], S[1]);
        if (S[2] != 0.f) unsafeAtomicAdd(&fa[6], S[2]);
#else
        if (S[0] != 0.f) atomicAdd(&fa[4], S[0]);
        if (S[1] != 0.f) atomicAdd(&fa[5], S[1]);
        if (S[2] != 0.f) atomicAdd(&fa[6], S[2]);
#endif
    }
}

// ---------------- finalize ----------------
__global__ void finalize_kernel(const u32* __restrict__ acc, float* __restrict__ out)
{
    if (blockIdx.x == 0 && threadIdx.x == 0) {
        double S = 0.0, C = 0.0;
        for (int s = 0; s < NSAMP; ++s) {
            const u32* a = acc + s * ACC_STRIDE;
            const float* fa = (const float*)a;
            long long nobs = (long long)a[0];
            long long cz   = (long long)a[1];
            long long chi  = (long long)a[2];
            long long cx   = (long long)a[3];
            double sz = fa[4], shi = fa[5], sx = fa[6];
            long long k = (long long)rintf(0.1f * (float)nobs);   // jnp.round semantics
            long long need = k - chi;
            if (need < 0) need = 0;
            if (need > cx) need = cx;
            double frac = cx > 0 ? (double)need / (double)cx : 0.0;
            S += shi + frac * sx + sz;
            C += (double)(chi + need + cz);
        }
        out[0] = (float)(S / (C > 0.0 ? C : 1.0));
    }
}

extern "C" void kernel_launch(void* const* d_in, const int* in_sizes, int n_in,
                              void* d_out, int out_size, void* d_ws, size_t ws_size,
                              hipStream_t stream)
{
    const float* data = (const float*)d_in[0];
    const float* mask = (const float*)d_in[1];
    const float* rnd  = (const float*)d_in[4];
    const float* xe   = (const float*)d_in[5];
    const float* ye   = (const float*)d_in[6];
    const float* w1   = (const float*)d_in[7];
    const float* b1   = (const float*)d_in[8];
    const float* w2   = (const float*)d_in[9];
    const float* b2   = (const float*)d_in[10];
    float* out = (float*)d_out;

    char* ws = (char*)d_ws;
    float* pred   = (float*)(ws);               // 65536 B
    u32*   ghist  = (u32*)(ws + 65536);         // 65536 B
    u32*   gobs   = (u32*)(ws + 131072);        // 32 B
    int*   bx     = (int*)(ws + 131104);        // 32 B
    u32*   acc    = (u32*)(ws + 131136);        // 256 B
    uint4* bitmap = (uint4*)(ws + 131392);      // NPS*NSAMP/16*4 = 8388608 B

    hipMemsetAsync(ws + 65536, 0, 65536 + 32 + 32 + 256, stream);

    dim3 g1(PBPS, NSAMP);
    phase1_hist<<<g1, 256, 0, stream>>>(mask, rnd, ghist, gobs);
    phase1_select<<<NSAMP, 256, 0, stream>>>(ghist, gobs, bx);
    impute_kernel<<<(PREDN + 255) / 256, 256, 0, stream>>>(xe, ye, w1, b1, w2, b2, pred);

    dim3 g2(BPS, NSAMP);
    passA_kernel<<<g2, 256, 0, stream>>>(mask, rnd, bx, bitmap, acc);
    passB_kernel<<<g2, 256, 0, stream>>>(data, pred, bitmap, acc);

    finalize_kernel<<<1, 64, 0, stream>>>(acc, out);
}